// Round 12
// baseline (141.092 us; speedup 1.0000x reference)
//
#include <hip/hip_runtime.h>
#include <hip/hip_bf16.h>
#include <math.h>
#include <stdint.h>

#define NN 8192
#define KK 128
#define DD 128
#define KG 4             // k-components per gemm block
#define NGRP (KK / KG)   // 32 k-groups
#define RPB 512          // n-rows per gemm block (4 waves x 128 rows)
#define NBLK (NN / RPB)  // 16

typedef int   i32x8  __attribute__((ext_vector_type(8)));
typedef float f32x4  __attribute__((ext_vector_type(4)));
typedef float f32x16 __attribute__((ext_vector_type(16)));
typedef __attribute__((address_space(3))) uint32_t lds_u32;
typedef const __attribute__((address_space(1))) uint32_t glb_u32;

// Fragment-order byte address of M element (i=m-row, j=k-dim) within one k's 16KB:
//   (i>>5)*4096 [mtile] + ((j>>6)&1)*2048 [kstep] + ((j>>4)&1)*1024 [sub]
// + ((j>>5)&1)*512 [lane-half] + (i&31)*16 + (j&15)
// -> wave A-frag ds_read_b128s conflict-free; staging is the identity map.

// ---------------- prep: fused. slice<8: M_k fp8 fragment-order + nbvec + cvec.
// slice==8: quantize 64 rows of X to fp8 (natural order = B-frag order).
// grid (KK, 9) x 256. Block(0,0) zeroes d_out (runs before gemm on the stream).
__global__ __launch_bounds__(256) void prep(const float* __restrict__ X,
                                            const float* __restrict__ means,
                                            const float* __restrict__ logvar,
                                            const float* __restrict__ tri,
                                            const float* __restrict__ weigh,
                                            uint8_t* __restrict__ M8,
                                            uint8_t* __restrict__ Xq,
                                            float* __restrict__ nbvec,
                                            float* __restrict__ cvec,
                                            float* __restrict__ out) {
    int k = blockIdx.x, slice = blockIdx.y;
    int t = threadIdx.x;

    if (slice == 8) {   // X-quantize: rows [k*64, k*64+64)
        const float4* src = (const float4*)(X + (size_t)k * 64 * DD);
        uint32_t*     dst = (uint32_t*)(Xq + (size_t)k * 64 * DD);
#pragma unroll
        for (int r = 0; r < 8; r++) {
            int idx = r * 256 + t;
            float4 f = src[idx];
            int pk = __builtin_amdgcn_cvt_pk_fp8_f32(f.x, f.y, 0, 0);
            pk     = __builtin_amdgcn_cvt_pk_fp8_f32(f.z, f.w, pk, 1);
            dst[idx] = (uint32_t)pk;
        }
        return;
    }

    if (k == 0 && slice == 0 && t == 0) out[0] = 0.f;
    __shared__ float svar[DD], smean[DD], red[DD];
    if (t < DD) {
        float var = expf(tanhf(logvar[k * DD + t]));
        svar[t]  = var;
        smean[t] = means[k * DD + t];
        red[t]   = logf(var + 1e-8f);
    }
    __syncthreads();

    int w = t >> 6, lane = t & 63;
    const float* trik = tri + (size_t)k * DD * DD;
    uint8_t* Mk = M8 + ((size_t)k << 14);
#pragma unroll
    for (int rr = 0; rr < 4; rr++) {
        int i = slice * 16 + w * 4 + rr;
        int j0 = lane, j1 = lane + 64;
        float m0 = (j0 < i) ? trik[i * DD + j0] * svar[j0] : ((j0 == i) ? svar[j0] : 0.f);
        float m1 = (j1 < i) ? trik[i * DD + j1] * svar[j1] : ((j1 == i) ? svar[j1] : 0.f);
        int pk = __builtin_amdgcn_cvt_pk_fp8_f32(m0, m1, 0, 0);
        int f0 = (i >> 5) * 4096 + ((lane >> 4) & 1) * 1024 + ((lane >> 5) & 1) * 512
               + (i & 31) * 16 + (lane & 15);
        Mk[f0]        = (uint8_t)(pk & 0xFF);          // j0: kstep 0
        Mk[f0 + 2048] = (uint8_t)((pk >> 8) & 0xFF);   // j1 = j0+64: kstep 1
        float b = m0 * smean[j0] + m1 * smean[j1];
#pragma unroll
        for (int off = 32; off; off >>= 1) b += __shfl_xor(b, off, 64);
        if (lane == 0) nbvec[k * DD + i] = -b;
    }

    __syncthreads();
    if (slice == 0 && t < 64) {
        float ld = red[t] + red[t + 64];
#pragma unroll
        for (int off = 32; off; off >>= 1) ld += __shfl_xor(ld, off, 64);
        float w0 = weigh[t], w1 = weigh[t + 64];
        float mx = fmaxf(w0, w1);
#pragma unroll
        for (int off = 32; off; off >>= 1) mx = fmaxf(mx, __shfl_xor(mx, off, 64));
        float e = expf(w0 - mx) + expf(w1 - mx);
#pragma unroll
        for (int off = 32; off; off >>= 1) e += __shfl_xor(e, off, 64);
        if (t == 0) cvec[k] = ld + weigh[k] - (mx + logf(e));
    }
}

// ---------------- gemm_lse: 32x32x64 MX-fp8, single-stage LDS, barrier-free MFMA
// loop + fused running LSE + LAST-DONE-BLOCK finalize (no spin, no ordering
// assumption). grid (16, 32) x 256.
__global__ __launch_bounds__(256, 2) void gemm_lse(const uint8_t* __restrict__ Xq,
                                                   const uint8_t* __restrict__ M8,
                                                   const float* __restrict__ nbvec,
                                                   const float* __restrict__ cvec,
                                                   float* __restrict__ pm,
                                                   float* __restrict__ ps,
                                                   uint32_t* __restrict__ ctrA,
                                                   const uint32_t* __restrict__ ctrB,
                                                   float* __restrict__ out) {
    __shared__ char smem[67584];   // [0,64K) A frags (4 k's) | [64K,+2K) nb
    float* nb = (float*)(smem + 65536);

    int tid = threadIdx.x;
    int w = tid >> 6, lane = tid & 63;
    int h = lane >> 5, l31 = lane & 31;
    int nblk = blockIdx.x, kg = blockIdx.y;
    int n0 = nblk * RPB, k0 = kg * KG;

    // issue ALL staging first (64 KB, identity map: 16 passes x 256 thr x 16B)
    const uint8_t* gk0 = M8 + ((size_t)k0 << 14);
#pragma unroll
    for (int p = 0; p < 16; p++)
        __builtin_amdgcn_global_load_lds((glb_u32*)(gk0 + p * 4096 + tid * 16),
                                         (lds_u32*)(smem + p * 4096 + w * 1024),
                                         16, 0, 0);

    ((float2*)nb)[tid] = ((const float2*)(nbvec + (k0 << 7)))[tid];
    float ckv[KG];
#pragma unroll
    for (int kk = 0; kk < KG; kk++) ckv[kk] = cvec[k0 + kk];

    // X fragments (B-operand) from Xq — overlap the staging drain.
    i32x8 Xf[4][2];
#pragma unroll
    for (int nt = 0; nt < 4; nt++) {
        int row = n0 + w * 128 + nt * 32 + l31;
        const uint8_t* xr = Xq + (size_t)row * DD + h * 32;
#pragma unroll
        for (int ks = 0; ks < 2; ks++) {
            uint4 a = *(const uint4*)(xr + ks * 64);
            uint4 b = *(const uint4*)(xr + ks * 64 + 16);
            Xf[nt][ks] = (i32x8){(int)a.x, (int)a.y, (int)a.z, (int)a.w,
                                 (int)b.x, (int)b.y, (int)b.z, (int)b.w};
        }
    }

    float rm[4], rsum[4], qv[4];
#pragma unroll
    for (int nt = 0; nt < 4; nt++) { rm[nt] = -INFINITY; rsum[nt] = 0.f; qv[nt] = 0.f; }

    __syncthreads();   // the ONLY compute barrier: staging + nb visible

    const char* fb = smem + h * 512 + l31 * 16;

    uint4 pa0 = *(const uint4*)(fb);
    uint4 pa1 = *(const uint4*)(fb + 1024);
    uint4 pa2 = *(const uint4*)(fb + 2048);
    uint4 pa3 = *(const uint4*)(fb + 3072);

#pragma unroll
    for (int t = 0; t < KG * 4; t++) {
        const int kk = t >> 2, mt = t & 3;
        uint4 a00 = pa0, a01 = pa1, a10 = pa2, a11 = pa3;
        if (t + 1 < KG * 4) {
            const char* bn = fb + ((t + 1) >> 2) * 16384 + ((t + 1) & 3) * 4096;
            pa0 = *(const uint4*)(bn);
            pa1 = *(const uint4*)(bn + 1024);
            pa2 = *(const uint4*)(bn + 2048);
            pa3 = *(const uint4*)(bn + 3072);
        }
        i32x8 A0 = {(int)a00.x, (int)a00.y, (int)a00.z, (int)a00.w,
                    (int)a01.x, (int)a01.y, (int)a01.z, (int)a01.w};
        i32x8 A1 = {(int)a10.x, (int)a10.y, (int)a10.z, (int)a10.w,
                    (int)a11.x, (int)a11.y, (int)a11.z, (int)a11.w};

        const float* nbb = nb + (kk << 7) + mt * 32 + h * 4;
        f32x4 c0 = *(const f32x4*)(nbb);
        f32x4 c1 = *(const f32x4*)(nbb + 8);
        f32x4 c2 = *(const f32x4*)(nbb + 16);
        f32x4 c3 = *(const f32x4*)(nbb + 24);
        f32x16 cin;
#pragma unroll
        for (int q = 0; q < 4; q++) {
            cin[q] = c0[q]; cin[4 + q] = c1[q]; cin[8 + q] = c2[q]; cin[12 + q] = c3[q];
        }

#pragma unroll
        for (int nt = 0; nt < 4; nt++) {
            f32x16 acc = __builtin_amdgcn_mfma_scale_f32_32x32x64_f8f6f4(
                A0, Xf[nt][0], cin, 0, 0, 0, 0x7F7F7F7F, 0, 0x7F7F7F7F);
            acc = __builtin_amdgcn_mfma_scale_f32_32x32x64_f8f6f4(
                A1, Xf[nt][1], acc, 0, 0, 0, 0x7F7F7F7F, 0, 0x7F7F7F7F);
#pragma unroll
            for (int r = 0; r < 16; r++) qv[nt] = fmaf(acc[r], acc[r], qv[nt]);
        }

        if (mt == 3) {
#pragma unroll
            for (int nt = 0; nt < 4; nt++) {
                float q = qv[nt] + __shfl_xor(qv[nt], 32, 64);
                float v = fmaf(q, -0.5f, ckv[kk]);
                float nm = fmaxf(rm[nt], v);
                rsum[nt] = rsum[nt] * __expf(rm[nt] - nm) + __expf(v - nm);
                rm[nt] = nm;
                qv[nt] = 0.f;
            }
        }
    }

    if (h == 0) {
#pragma unroll
        for (int nt = 0; nt < 4; nt++) {
            int idx = kg * NN + n0 + w * 128 + nt * 32 + l31;
            pm[idx] = rm[nt];
            ps[idx] = rsum[nt];
        }
    }

    // ---- last-done-block finalize for this n-range ----
    __threadfence();                 // release pm/ps device-wide
    __syncthreads();                 // all threads' stores issued+fenced
    __shared__ uint32_t sdone;
    if (tid == 0) {
        uint32_t old = __hip_atomic_fetch_add(&ctrA[nblk], 1u, __ATOMIC_ACQ_REL,
                                              __HIP_MEMORY_SCOPE_AGENT);
        sdone = old - ctrB[nblk];    // #blocks of this nblk finished before me
    }
    __syncthreads();
    if (sdone != (uint32_t)(NGRP - 1)) return;   // not the last -> done

    // merger: 256 threads, 2 rows each; agent-scope loads (cross-XCD safe)
    float contrib = 0.f;
#pragma unroll
    for (int rr = 0; rr < 2; rr++) {
        int n = n0 + rr * 256 + tid;
        float M = -INFINITY, S = 0.f;
#pragma unroll 4
        for (int g = 0; g < NGRP; g++) {
            float m = __hip_atomic_load(&pm[(size_t)g * NN + n], __ATOMIC_RELAXED,
                                        __HIP_MEMORY_SCOPE_AGENT);
            float s = __hip_atomic_load(&ps[(size_t)g * NN + n], __ATOMIC_RELAXED,
                                        __HIP_MEMORY_SCOPE_AGENT);
            float nm = fmaxf(M, m);
            S = S * __expf(M - nm) + s * __expf(m - nm);
            M = nm;
        }
        float lse = M + logf(S);
        const float logC = -64.f * 1.8378770664093453f;
        contrib += (-logC - lse) * (1.f / (float)NN);
    }
    float* sred = (float*)smem;      // reuse LDS (compute phase is over)
    sred[tid] = contrib;
    __syncthreads();
    for (int off = 128; off > 0; off >>= 1) {
        if (tid < off) sred[tid] += sred[tid + off];
        __syncthreads();
    }
    if (tid == 0) atomicAdd(out, sred[0]);
}

extern "C" void kernel_launch(void* const* d_in, const int* in_sizes, int n_in,
                              void* d_out, int out_size, void* d_ws, size_t ws_size,
                              hipStream_t stream) {
    const float* X      = (const float*)d_in[0];
    const float* means  = (const float*)d_in[1];
    const float* logvar = (const float*)d_in[2];
    const float* tri    = (const float*)d_in[3];
    const float* weigh  = (const float*)d_in[4];
    float* out = (float*)d_out;

    char* ws = (char*)d_ws;
    uint8_t*  M8    = (uint8_t*)(ws);                 // 2 MiB
    float*    nbvec = (float*)(ws + 2097152);         // 64 KiB
    float*    cvec  = (float*)(ws + 2162688);         // 2 KiB pad
    float*    pm    = (float*)(ws + 2164736);         // 1 MiB (32 x 8192)
    float*    ps    = (float*)(ws + 3213312);         // 1 MiB
    uint8_t*  Xq    = (uint8_t*)(ws + 4261888);       // 1 MiB
    uint32_t* ctrA  = (uint32_t*)(ws + 5310464);      // 64 B (16 counters)
    uint32_t* ctrB  = (uint32_t*)(ws + 5310720);      // 64 B untouched twin

    prep<<<dim3(KK, 9), 256, 0, stream>>>(X, means, logvar, tri, weigh,
                                          M8, Xq, nbvec, cvec, out);
    gemm_lse<<<dim3(NBLK, NGRP), 256, 0, stream>>>(Xq, M8, nbvec, cvec,
                                                   pm, ps, ctrA, ctrB, out);
}

// Round 13
// 96.691 us; speedup vs baseline: 1.4592x; 1.4592x over previous
//
#include <hip/hip_runtime.h>
#include <hip/hip_bf16.h>
#include <math.h>
#include <stdint.h>

#define NN 8192
#define KK 128
#define DD 128
#define KG 4             // k-components per gemm block
#define NGRP (KK / KG)   // 32 k-groups
#define RPB 512          // n-rows per gemm block (4 waves x 128 rows)
#define NBLK (NN / RPB)  // 16

typedef int   i32x8  __attribute__((ext_vector_type(8)));
typedef float f32x4  __attribute__((ext_vector_type(4)));
typedef float f32x16 __attribute__((ext_vector_type(16)));
typedef __attribute__((address_space(3))) uint32_t lds_u32;
typedef const __attribute__((address_space(1))) uint32_t glb_u32;

// Fragment-order byte address of M element (i=m-row, j=k-dim) within one k's 16KB:
//   (i>>5)*4096 [mtile] + ((j>>6)&1)*2048 [kstep] + ((j>>4)&1)*1024 [sub]
// + ((j>>5)&1)*512 [lane-half] + (i&31)*16 + (j&15)
// -> wave A-frag ds_read_b128s conflict-free; staging is the identity map.

// ---------------- prep: fused. slice<8: M_k fp8 fragment-order + nbvec + cvec.
// slice==8: quantize 64 rows of X to fp8 (natural order = B-frag order).
// grid (KK, 9) x 256. Block(0,0) zeroes d_out (runs before finalize on stream).
__global__ __launch_bounds__(256) void prep(const float* __restrict__ X,
                                            const float* __restrict__ means,
                                            const float* __restrict__ logvar,
                                            const float* __restrict__ tri,
                                            const float* __restrict__ weigh,
                                            uint8_t* __restrict__ M8,
                                            uint8_t* __restrict__ Xq,
                                            float* __restrict__ nbvec,
                                            float* __restrict__ cvec,
                                            float* __restrict__ out) {
    int k = blockIdx.x, slice = blockIdx.y;
    int t = threadIdx.x;

    if (slice == 8) {   // X-quantize: rows [k*64, k*64+64)
        const float4* src = (const float4*)(X + (size_t)k * 64 * DD);
        uint32_t*     dst = (uint32_t*)(Xq + (size_t)k * 64 * DD);
#pragma unroll
        for (int r = 0; r < 8; r++) {
            int idx = r * 256 + t;
            float4 f = src[idx];
            int pk = __builtin_amdgcn_cvt_pk_fp8_f32(f.x, f.y, 0, 0);
            pk     = __builtin_amdgcn_cvt_pk_fp8_f32(f.z, f.w, pk, 1);
            dst[idx] = (uint32_t)pk;
        }
        return;
    }

    if (k == 0 && slice == 0 && t == 0) out[0] = 0.f;
    __shared__ float svar[DD], smean[DD], red[DD];
    if (t < DD) {
        float var = expf(tanhf(logvar[k * DD + t]));
        svar[t]  = var;
        smean[t] = means[k * DD + t];
        red[t]   = logf(var + 1e-8f);
    }
    __syncthreads();

    int w = t >> 6, lane = t & 63;
    const float* trik = tri + (size_t)k * DD * DD;
    uint8_t* Mk = M8 + ((size_t)k << 14);
#pragma unroll
    for (int rr = 0; rr < 4; rr++) {
        int i = slice * 16 + w * 4 + rr;
        int j0 = lane, j1 = lane + 64;
        float m0 = (j0 < i) ? trik[i * DD + j0] * svar[j0] : ((j0 == i) ? svar[j0] : 0.f);
        float m1 = (j1 < i) ? trik[i * DD + j1] * svar[j1] : ((j1 == i) ? svar[j1] : 0.f);
        int pk = __builtin_amdgcn_cvt_pk_fp8_f32(m0, m1, 0, 0);
        int f0 = (i >> 5) * 4096 + ((lane >> 4) & 1) * 1024 + ((lane >> 5) & 1) * 512
               + (i & 31) * 16 + (lane & 15);
        Mk[f0]        = (uint8_t)(pk & 0xFF);          // j0: kstep 0
        Mk[f0 + 2048] = (uint8_t)((pk >> 8) & 0xFF);   // j1 = j0+64: kstep 1
        float b = m0 * smean[j0] + m1 * smean[j1];
#pragma unroll
        for (int off = 32; off; off >>= 1) b += __shfl_xor(b, off, 64);
        if (lane == 0) nbvec[k * DD + i] = -b;
    }

    __syncthreads();
    if (slice == 0 && t < 64) {
        float ld = red[t] + red[t + 64];
#pragma unroll
        for (int off = 32; off; off >>= 1) ld += __shfl_xor(ld, off, 64);
        float w0 = weigh[t], w1 = weigh[t + 64];
        float mx = fmaxf(w0, w1);
#pragma unroll
        for (int off = 32; off; off >>= 1) mx = fmaxf(mx, __shfl_xor(mx, off, 64));
        float e = expf(w0 - mx) + expf(w1 - mx);
#pragma unroll
        for (int off = 32; off; off >>= 1) e += __shfl_xor(e, off, 64);
        if (t == 0) cvec[k] = ld + weigh[k] - (mx + logf(e));
    }
}

// ---------------- gemm_q: 32x32x64 MX-fp8, ALL 4 k's (64KB) staged to LDS once,
// then a barrier-free flattened (kk,mt) MFMA loop with one-step ds_read prefetch.
// X pre-quantized -> B-fragments are direct 32B fp8 loads. NO cross-block
// coherence traffic (R12 lesson: device fences/atomics in-kernel cost ~55us).
// grid (16, 32) x 256. Wave w: rows n0+w*128..+127 (nt=4 x 32), all 128 M-rows.
__global__ __launch_bounds__(256, 2) void gemm_q(const uint8_t* __restrict__ Xq,
                                                 const uint8_t* __restrict__ M8,
                                                 const float* __restrict__ nbvec,
                                                 const float* __restrict__ cvec,
                                                 float* __restrict__ pm,
                                                 float* __restrict__ ps) {
    __shared__ char smem[67584];   // [0,64K) A frags (4 k's) | [64K,+2K) nb
    float* nb = (float*)(smem + 65536);

    int tid = threadIdx.x;
    int w = tid >> 6, lane = tid & 63;
    int h = lane >> 5, l31 = lane & 31;
    int nblk = blockIdx.x, kg = blockIdx.y;
    int n0 = nblk * RPB, k0 = kg * KG;

    // issue ALL staging first (64 KB, identity map: 16 passes x 256 thr x 16B)
    const uint8_t* gk0 = M8 + ((size_t)k0 << 14);
#pragma unroll
    for (int p = 0; p < 16; p++)
        __builtin_amdgcn_global_load_lds((glb_u32*)(gk0 + p * 4096 + tid * 16),
                                         (lds_u32*)(smem + p * 4096 + w * 1024),
                                         16, 0, 0);

    ((float2*)nb)[tid] = ((const float2*)(nbvec + (k0 << 7)))[tid];
    float ckv[KG];
#pragma unroll
    for (int kk = 0; kk < KG; kk++) ckv[kk] = cvec[k0 + kk];

    // X fragments (B-operand) from Xq — overlap the staging drain.
    // B[k][n]: n=l31, k = ks*64 + h*32 + reg*4 + byte  (natural row-byte order)
    i32x8 Xf[4][2];
#pragma unroll
    for (int nt = 0; nt < 4; nt++) {
        int row = n0 + w * 128 + nt * 32 + l31;
        const uint8_t* xr = Xq + (size_t)row * DD + h * 32;
#pragma unroll
        for (int ks = 0; ks < 2; ks++) {
            uint4 a = *(const uint4*)(xr + ks * 64);
            uint4 b = *(const uint4*)(xr + ks * 64 + 16);
            Xf[nt][ks] = (i32x8){(int)a.x, (int)a.y, (int)a.z, (int)a.w,
                                 (int)b.x, (int)b.y, (int)b.z, (int)b.w};
        }
    }

    float rm[4], rsum[4], qv[4];
#pragma unroll
    for (int nt = 0; nt < 4; nt++) { rm[nt] = -INFINITY; rsum[nt] = 0.f; qv[nt] = 0.f; }

    __syncthreads();   // the ONLY barrier: all staging + nb visible

    const char* fb = smem + h * 512 + l31 * 16;   // lane's fragment base

    // prefetch step 0
    uint4 pa0 = *(const uint4*)(fb);
    uint4 pa1 = *(const uint4*)(fb + 1024);
    uint4 pa2 = *(const uint4*)(fb + 2048);
    uint4 pa3 = *(const uint4*)(fb + 3072);

#pragma unroll
    for (int t = 0; t < KG * 4; t++) {
        const int kk = t >> 2, mt = t & 3;
        uint4 a00 = pa0, a01 = pa1, a10 = pa2, a11 = pa3;
        if (t + 1 < KG * 4) {
            const char* bn = fb + ((t + 1) >> 2) * 16384 + ((t + 1) & 3) * 4096;
            pa0 = *(const uint4*)(bn);
            pa1 = *(const uint4*)(bn + 1024);
            pa2 = *(const uint4*)(bn + 2048);
            pa3 = *(const uint4*)(bn + 3072);
        }
        i32x8 A0 = {(int)a00.x, (int)a00.y, (int)a00.z, (int)a00.w,
                    (int)a01.x, (int)a01.y, (int)a01.z, (int)a01.w};
        i32x8 A1 = {(int)a10.x, (int)a10.y, (int)a10.z, (int)a10.w,
                    (int)a11.x, (int)a11.y, (int)a11.z, (int)a11.w};

        // C init = -b at row = mt*32 + (r&3) + 8*(r>>2) + 4*h
        const float* nbb = nb + (kk << 7) + mt * 32 + h * 4;
        f32x4 c0 = *(const f32x4*)(nbb);
        f32x4 c1 = *(const f32x4*)(nbb + 8);
        f32x4 c2 = *(const f32x4*)(nbb + 16);
        f32x4 c3 = *(const f32x4*)(nbb + 24);
        f32x16 cin;
#pragma unroll
        for (int q = 0; q < 4; q++) {
            cin[q] = c0[q]; cin[4 + q] = c1[q]; cin[8 + q] = c2[q]; cin[12 + q] = c3[q];
        }

#pragma unroll
        for (int nt = 0; nt < 4; nt++) {
            f32x16 acc = __builtin_amdgcn_mfma_scale_f32_32x32x64_f8f6f4(
                A0, Xf[nt][0], cin, 0, 0, 0, 0x7F7F7F7F, 0, 0x7F7F7F7F);
            acc = __builtin_amdgcn_mfma_scale_f32_32x32x64_f8f6f4(
                A1, Xf[nt][1], acc, 0, 0, 0, 0x7F7F7F7F, 0, 0x7F7F7F7F);
#pragma unroll
            for (int r = 0; r < 16; r++) qv[nt] = fmaf(acc[r], acc[r], qv[nt]);
        }

        if (mt == 3) {   // end of component kk: fold into running LSE
#pragma unroll
            for (int nt = 0; nt < 4; nt++) {
                float q = qv[nt] + __shfl_xor(qv[nt], 32, 64);
                float v = fmaf(q, -0.5f, ckv[kk]);
                float nm = fmaxf(rm[nt], v);
                rsum[nt] = rsum[nt] * __expf(rm[nt] - nm) + __expf(v - nm);
                rm[nt] = nm;
                qv[nt] = 0.f;
            }
        }
    }

    if (h == 0) {
#pragma unroll
        for (int nt = 0; nt < 4; nt++) {
            int idx = kg * NN + n0 + w * 128 + nt * 32 + l31;
            pm[idx] = rm[nt];
            ps[idx] = rsum[nt];
        }
    }
}

// ---------------- finalize: merge NGRP LSE partials per n, mean. 32 blocks x 256.
__global__ __launch_bounds__(256) void finalize(const float* __restrict__ pm,
                                                const float* __restrict__ ps,
                                                float* __restrict__ out) {
    __shared__ float sred[256];
    int t = threadIdx.x;
    int n = blockIdx.x * 256 + t;
    float M = -INFINITY, S = 0.f;
#pragma unroll 4
    for (int g = 0; g < NGRP; g++) {
        float m = pm[(size_t)g * NN + n];
        float s = ps[(size_t)g * NN + n];
        float nm = fmaxf(M, m);
        S = S * __expf(M - nm) + s * __expf(m - nm);
        M = nm;
    }
    float lse = M + logf(S);
    const float logC = -64.f * 1.8378770664093453f;
    sred[t] = (-logC - lse) * (1.f / (float)NN);
    __syncthreads();
    for (int off = 128; off > 0; off >>= 1) {
        if (t < off) sred[t] += sred[t + off];
        __syncthreads();
    }
    if (t == 0) atomicAdd(out, sred[0]);
}

extern "C" void kernel_launch(void* const* d_in, const int* in_sizes, int n_in,
                              void* d_out, int out_size, void* d_ws, size_t ws_size,
                              hipStream_t stream) {
    const float* X      = (const float*)d_in[0];
    const float* means  = (const float*)d_in[1];
    const float* logvar = (const float*)d_in[2];
    const float* tri    = (const float*)d_in[3];
    const float* weigh  = (const float*)d_in[4];
    float* out = (float*)d_out;

    char* ws = (char*)d_ws;
    uint8_t* M8    = (uint8_t*)(ws);                 // 2 MiB
    float*   nbvec = (float*)(ws + 2097152);         // 64 KiB
    float*   cvec  = (float*)(ws + 2162688);         // 2 KiB pad
    float*   pm    = (float*)(ws + 2164736);         // 1 MiB (32 x 8192)
    float*   ps    = (float*)(ws + 3213312);         // 1 MiB
    uint8_t* Xq    = (uint8_t*)(ws + 4261888);       // 1 MiB

    prep<<<dim3(KK, 9), 256, 0, stream>>>(X, means, logvar, tri, weigh,
                                          M8, Xq, nbvec, cvec, out);
    gemm_q<<<dim3(NBLK, NGRP), 256, 0, stream>>>(Xq, M8, nbvec, cvec, pm, ps);
    finalize<<<NN / 256, 256, 0, stream>>>(pm, ps, out);
}